// Round 5
// baseline (124.400 us; speedup 1.0000x reference)
//
#include <hip/hip_runtime.h>
#include <hip/hip_bf16.h>
#include <stdint.h>

#define B_    32
#define QLEN  1024
#define KSEQ  1024
#define DIM   128
#define NKT   (KSEQ / 64)              // 16 key-tiles of 64 per batch
#define SCALE 0.08838834764831845f     // 1/sqrt(128)

typedef __attribute__((ext_vector_type(8)))  short short8;
typedef __attribute__((ext_vector_type(4)))  float floatx4;
typedef __attribute__((ext_vector_type(16))) float floatx16;
typedef unsigned int u32;

__device__ __forceinline__ u32 f2bf(float x) {
  union { float f; u32 u; } v; v.f = x;
  return (v.u + 0x7FFF + ((v.u >> 16) & 1)) >> 16;   // RNE
}
__device__ __forceinline__ u32 pack2(float lo, float hi) {
  return f2bf(lo) | (f2bf(hi) << 16);
}
// v_cvt_pk_bf16_f32: dst.lo = bf16(lo), dst.hi = bf16(hi)  (RNE)
__device__ __forceinline__ u32 cvtpk(float lo, float hi) {
  u32 d;
  asm("v_cvt_pk_bf16_f32 %0, %1, %2" : "=v"(d) : "v"(lo), "v"(hi));
  return d;
}
// v_permlane32_swap_b32 a, b: a' = [a_lo, b_lo], b' = [a_hi, b_hi]
__device__ __forceinline__ void swap32(u32& a, u32& b) {
  asm volatile("v_permlane32_swap_b32 %0, %1" : "+v"(a), "+v"(b));
}
typedef union { uint4 u; short8 s; } U8;

__device__ __forceinline__ void barrier_full() {
  asm volatile("s_waitcnt vmcnt(0) lgkmcnt(0)" ::: "memory");
  __syncthreads();
}

// ---------------------------------------------------------------------------
// Prepass (unchanged from round 3): swizzled bf16 tile images in workspace.
//  K tiles:  [b][kt][row r=0..63][chunk c=0..15] at c ^ (r&15)
//  VT tiles: [b][kt][row d=0..127][chunk kc=0..7] at kc ^ (d&7)
// Block (z=0,kt=0,b=0) also builds the 512-entry complementary task table.
// ---------------------------------------------------------------------------
__global__ __launch_bounds__(256) void prep_kernel(const float* __restrict__ Kg,
                                                   const float* __restrict__ Vg,
                                                   const int* __restrict__ vlen,
                                                   uint4* __restrict__ Ksw,
                                                   uint4* __restrict__ Vsw,
                                                   int2* __restrict__ task) {
  __shared__ __align__(16) u32 Vu[64 * 65];
  __shared__ int sidx[32];
  const int kt = blockIdx.x, b = blockIdx.y, t = threadIdx.x;
  const bool tableblk = (blockIdx.z == 0) && (kt == 0) && (b == 0);

  if (tableblk && t < 64) {           // wave-parallel rank (reg-only)
    const int bb = t & 31;
    const int ntb = (vlen[bb] + 63) >> 6;
    int rank = 0;
#pragma unroll
    for (int j = 0; j < 32; j++) {
      const int ntj = __shfl(ntb, j);
      rank += (ntj > ntb) | ((ntj == ntb) & (j < bb));
    }
    if (t < 32) sidx[rank] = bb;
  }

  if (kt * 64 < vlen[b]) {
    if (blockIdx.z == 0) {
      const float* src = Kg + ((size_t)b * KSEQ + kt * 64) * DIM;
      uint4* dst = Ksw + ((size_t)b * NKT + kt) * 1024;
#pragma unroll
      for (int it = 0; it < 4; it++) {
        const int f = it * 256 + t, r = f >> 4, c = f & 15;
        floatx4 f0 = *(const floatx4*)(src + r * DIM + c * 8);
        floatx4 f1 = *(const floatx4*)(src + r * DIM + c * 8 + 4);
        uint4 o;
        o.x = pack2(f0[0], f0[1]); o.y = pack2(f0[2], f0[3]);
        o.z = pack2(f1[0], f1[1]); o.w = pack2(f1[2], f1[3]);
        dst[r * 16 + (c ^ (r & 15))] = o;
      }
    } else {
      const float* src = Vg + ((size_t)b * KSEQ + kt * 64) * DIM;
#pragma unroll
      for (int it = 0; it < 8; it++) {
        const int k = it * 8 + (t >> 5), c = t & 31;
        const floatx4 f = *(const floatx4*)(src + (size_t)k * DIM + c * 4);
        const int s = (k >> 3) & 4;
        Vu[k * 65 + ((2 * c) ^ s)]     = pack2(f[0], f[1]);
        Vu[k * 65 + ((2 * c + 1) ^ s)] = pack2(f[2], f[3]);
      }
      __syncthreads();
      uint4* dst = Vsw + ((size_t)b * NKT + kt) * 1024;
#pragma unroll
      for (int it = 0; it < 4; it++) {
        const int id = it * 256 + t;
        const int kc = id & 7, d = (id >> 3) & 127;
        const int col = (d >> 1) ^ (kc & 4);
        u32 r[8];
#pragma unroll
        for (int j = 0; j < 8; j++) r[j] = Vu[(kc * 8 + j) * 65 + col];
        const u32 sel = (d & 1) ? 0x07060302u : 0x05040100u;
        uint4 o;
        o.x = __builtin_amdgcn_perm(r[1], r[0], sel);
        o.y = __builtin_amdgcn_perm(r[3], r[2], sel);
        o.z = __builtin_amdgcn_perm(r[5], r[4], sel);
        o.w = __builtin_amdgcn_perm(r[7], r[6], sel);
        dst[d * 8 + (kc ^ (d & 7))] = o;
      }
    }
  }

  if (tableblk) {
    // Complementary table (QBLK=64, 512 tasks): XCD x gets ranks
    // {x,x+8,x+16,x+24}; breadth-first pairing (j, j+32) -> heavy+light/CU.
    __syncthreads();
    for (int l = t; l < 512; l += 256) {
      const int x = l & 7, j = l >> 3;
      int rank, q;
      if (j < 32) { rank = (j & 1) ? x + 8  : x;      q = j >> 1; }
      else        { rank = (j & 1) ? x + 16 : x + 24; q = (j - 32) >> 1; }
      task[l] = make_int2(sidx[rank], q << 6);
    }
  }
}

// ---------------------------------------------------------------------------
// Flash attention, 32x32x16 MFMA, swapped QK^T, register softmax.
// Block = 2 waves x 32 q = 64 q rows; grid 512 (task table), 2 blocks/CU.
// Per k-tile per wave: 16 K A-frag b128 reads (swapped QK^T: S[key][q]) +
// 16 V B-frag b128 reads; P never touches LDS: softmax is per-lane on the
// S-columns, then cvt_pk_bf16 pairs + permlane32_swap assemble the PV
// A-fragments in-register (T12). Fixed-max softmax p=exp(min(s*scale,30)),
// row-sum deferred; each lane's lrow covers half the keys of q=lane&31 and
// is completed by one shfl_xor(32) in the epilogue.
// ---------------------------------------------------------------------------
typedef const __attribute__((address_space(1))) u32* as1p;
typedef __attribute__((address_space(3))) u32* as3p;
__device__ __forceinline__ void gl_lds16(const void* g, void* l) {
  __builtin_amdgcn_global_load_lds((as1p)g, (as3p)l, 16, 0, 0);
}

__global__ __launch_bounds__(128, 1) void attn_kernel(
    const float* __restrict__ Qg, const uint4* __restrict__ Ksw,
    const uint4* __restrict__ Vsw, const int* __restrict__ vlen,
    const int2* __restrict__ task, float* __restrict__ Og) {
  __shared__ __align__(16) short Kbuf[2][64 * 128];     // 32 KB
  __shared__ __align__(16) short Vbuf[2][128 * 64];     // 32 KB

  const int2 tq = task[blockIdx.x];
  const int b = tq.x, q0 = tq.y;
  const int t = threadIdx.x, wave = t >> 6, lane = t & 63;
  const int l31 = lane & 31, hi = lane >> 5, m15 = l31 & 15, m7 = l31 & 7;
  const int L  = vlen[b];
  const int nt = (L + 63) >> 6;

  const char* Kt = (const char*)(Ksw + (size_t)b * NKT * 1024);
  const char* Vt = (const char*)(Vsw + (size_t)b * NKT * 1024);

  // ---- Q B-fragments: lane holds Q[q0+wave*32+l31][c*16+hi*8 .. +8] ----
  short8 qb[8];
  {
    const float* qrow = Qg + ((size_t)b * QLEN + q0 + wave * 32 + l31) * DIM;
#pragma unroll
    for (int c = 0; c < 8; c++) {
      floatx4 f0 = *(const floatx4*)(qrow + c * 16 + hi * 8);
      floatx4 f1 = *(const floatx4*)(qrow + c * 16 + hi * 8 + 4);
      short8 a;
      a[0] = (short)f2bf(f0[0]); a[1] = (short)f2bf(f0[1]);
      a[2] = (short)f2bf(f0[2]); a[3] = (short)f2bf(f0[3]);
      a[4] = (short)f2bf(f1[0]); a[5] = (short)f2bf(f1[1]);
      a[6] = (short)f2bf(f1[2]); a[7] = (short)f2bf(f1[3]);
      qb[c] = a;
    }
  }

  float lrow = 0.0f;
  floatx16 oacc[4];
#pragma unroll
  for (int dt = 0; dt < 4; dt++)
#pragma unroll
    for (int i = 0; i < 16; i++) oacc[dt][i] = 0.0f;

  // per-wave DMA slices: wave w stages bytes [w*8192, w*8192+8192) of each tile
#define ISSUE_K(tk, bb)                                                        \
  {                                                                            \
    const char* g_ = Kt + (size_t)(tk) * 16384 + wave * 8192 + lane * 16;      \
    _Pragma("unroll") for (int i_ = 0; i_ < 8; i_++)                           \
        gl_lds16(g_ + i_ * 1024, (char*)Kbuf[bb] + wave * 8192 + i_ * 1024);   \
  }
#define ISSUE_V(tk, bb)                                                        \
  {                                                                            \
    const char* g_ = Vt + (size_t)(tk) * 16384 + wave * 8192 + lane * 16;      \
    _Pragma("unroll") for (int i_ = 0; i_ < 8; i_++)                           \
        gl_lds16(g_ + i_ * 1024, (char*)Vbuf[bb] + wave * 8192 + i_ * 1024);   \
  }

  ISSUE_K(0, 0);
  ISSUE_V(0, 0);

  // pa words for PV from S-cols (keys avail per lane: {0-3,8-11,16-19,24-27}+4hi):
  // w0=(0,1)/(8,9), w1=(2,3)/(10,11), w2=(4,5)/(12,13), w3=(6,7)/(14,15)
#define PV_TILE(SV, KC0, KC1)                                                  \
  {                                                                            \
    u32 u0 = cvtpk(SV[0], SV[1]),   u1 = cvtpk(SV[2], SV[3]);                  \
    u32 u2 = cvtpk(SV[4], SV[5]),   u3 = cvtpk(SV[6], SV[7]);                  \
    swap32(u0, u2); swap32(u1, u3);                                            \
    u32 w0 = cvtpk(SV[8], SV[9]),   w1 = cvtpk(SV[10], SV[11]);                \
    u32 w2 = cvtpk(SV[12], SV[13]), w3 = cvtpk(SV[14], SV[15]);                \
    swap32(w0, w2); swap32(w1, w3);                                            \
    U8 pu0; pu0.u.x = u0; pu0.u.y = u1; pu0.u.z = u2; pu0.u.w = u3;            \
    U8 pu1; pu1.u.x = w0; pu1.u.y = w1; pu1.u.z = w2; pu1.u.w = w3;            \
    __builtin_amdgcn_s_setprio(1);                                             \
    _Pragma("unroll") for (int dt = 0; dt < 4; dt++) {                         \
      const short* vr_ = Vb_ + (dt * 32 + l31) * 64;                           \
      const short8 b0_ = *(const short8*)(vr_ + ((KC0) ^ m7) * 8);             \
      oacc[dt] = __builtin_amdgcn_mfma_f32_32x32x16_bf16(pu0.s, b0_, oacc[dt], 0, 0, 0); \
      const short8 b1_ = *(const short8*)(vr_ + ((KC1) ^ m7) * 8);             \
      oacc[dt] = __builtin_amdgcn_mfma_f32_32x32x16_bf16(pu1.s, b1_, oacc[dt], 0, 0, 0); \
    }                                                                          \
    __builtin_amdgcn_s_setprio(0);                                             \
  }

  for (int tk = 0; tk < nt; tk++) {
    const int k0 = tk * 64;
    barrier_full();                        // DMA(tk) landed; buf[(tk+1)&1] free
    if (tk + 1 < nt) {
      ISSUE_K(tk + 1, (tk + 1) & 1);
      ISSUE_V(tk + 1, (tk + 1) & 1);
    }
    const short* Kb_ = Kbuf[tk & 1];
    const short* Vb_ = Vbuf[tk & 1];

    // ---- swapped S = K Q^T : S[key][q], two 32-key tiles ----
    floatx16 s0, s1;
#pragma unroll
    for (int i = 0; i < 16; i++) { s0[i] = 0.0f; s1[i] = 0.0f; }
    {
      const short* kr0 = Kb_ + l31 * 128;          // keys 0-31  (row&15 = m15)
      const short* kr1 = Kb_ + (32 + l31) * 128;   // keys 32-63 (row&15 = m15)
      __builtin_amdgcn_s_setprio(1);
#pragma unroll
      for (int c = 0; c < 8; c++) {
        const int cp = ((2 * c + hi) ^ m15) * 8;
        const short8 ka0 = *(const short8*)(kr0 + cp);
        const short8 ka1 = *(const short8*)(kr1 + cp);
        s0 = __builtin_amdgcn_mfma_f32_32x32x16_bf16(ka0, qb[c], s0, 0, 0, 0);
        s1 = __builtin_amdgcn_mfma_f32_32x32x16_bf16(ka1, qb[c], s1, 0, 0, 0);
      }
      __builtin_amdgcn_s_setprio(0);
    }

    // ---- fixed-max softmax in-place: p = exp(min(s*SCALE,30)), mask -> 0 ----
    if (k0 + 64 <= L) {
#pragma unroll
      for (int r = 0; r < 16; r++) {
        s0[r] = __expf(fminf(s0[r] * SCALE, 30.0f));
        s1[r] = __expf(fminf(s1[r] * SCALE, 30.0f));
        lrow += s0[r] + s1[r];
      }
    } else {
#pragma unroll
      for (int r = 0; r < 16; r++) {
        const int ck = (r & 3) + 8 * (r >> 2) + 4 * hi;   // key within tile
        const float a0 = (k0 + ck < L)      ? __expf(fminf(s0[r] * SCALE, 30.0f)) : 0.0f;
        const float a1 = (k0 + 32 + ck < L) ? __expf(fminf(s1[r] * SCALE, 30.0f)) : 0.0f;
        s0[r] = a0; s1[r] = a1;
        lrow += a0 + a1;
      }
    }

    // ---- O += P V : in-register P fragments, VT image B-frags ----
    PV_TILE(s0, 0 + hi, 2 + hi);     // keys  0..31: k-chunks 0/1 (+hi)
    PV_TILE(s1, 4 + hi, 6 + hi);     // keys 32..63: k-chunks 4/5 (+hi)
  }

  // ---- epilogue: complete row sums, normalize, store ----
  lrow += __shfl_xor(lrow, 32);      // lane l and l^32 hold complementary keys
  const float inv_ = 1.0f / lrow;    // inv for q = l31 (valid on all lanes)
  float iv[16];
#pragma unroll
  for (int r = 0; r < 16; r++)
    iv[r] = __shfl(inv_, (r & 3) + 8 * (r >> 2) + 4 * hi);
  float* obase = Og + ((size_t)b * QLEN + q0 + wave * 32) * DIM + l31;
#pragma unroll
  for (int dt = 0; dt < 4; dt++) {
#pragma unroll
    for (int r = 0; r < 16; r++) {
      const int rq = (r & 3) + 8 * (r >> 2) + 4 * hi;
      obase[(size_t)rq * DIM + dt * 32] = oacc[dt][r] * iv[r];
    }
  }
#undef ISSUE_K
#undef ISSUE_V
#undef PV_TILE
}

extern "C" void kernel_launch(void* const* d_in, const int* in_sizes, int n_in,
                              void* d_out, int out_size, void* d_ws, size_t ws_size,
                              hipStream_t stream) {
  const float* Qg = (const float*)d_in[0];
  const float* Kg = (const float*)d_in[1];
  const float* Vg = (const float*)d_in[2];
  const int*  vln = (const int*)d_in[3];
  uint4* Ksw = (uint4*)d_ws;                                      // 8 MiB
  uint4* Vsw = (uint4*)((char*)d_ws + (size_t)B_ * NKT * 16384);  // 8 MiB
  int2*  Tsk = (int2*)((char*)d_ws + 2 * (size_t)B_ * NKT * 16384);

  prep_kernel<<<dim3(NKT, B_, 2), 256, 0, stream>>>(Kg, Vg, vln, Ksw, Vsw, Tsk);
  attn_kernel<<<dim3(512), 128, 0, stream>>>(Qg, Ksw, Vsw, vln, Tsk,
                                             (float*)d_out);
}

// Round 6
// 116.819 us; speedup vs baseline: 1.0649x; 1.0649x over previous
//
#include <hip/hip_runtime.h>
#include <hip/hip_bf16.h>
#include <stdint.h>

#define B_    32
#define QLEN  1024
#define KSEQ  1024
#define DIM   128
#define NKT   (KSEQ / 64)              // 16 key-tiles of 64 per batch
#define SCALE 0.08838834764831845f     // 1/sqrt(128)

typedef __attribute__((ext_vector_type(8)))  short short8;
typedef __attribute__((ext_vector_type(4)))  float floatx4;
typedef __attribute__((ext_vector_type(16))) float floatx16;
typedef unsigned int u32;

__device__ __forceinline__ u32 f2bf(float x) {
  union { float f; u32 u; } v; v.f = x;
  return (v.u + 0x7FFF + ((v.u >> 16) & 1)) >> 16;   // RNE
}
__device__ __forceinline__ u32 pack2(float lo, float hi) {
  return f2bf(lo) | (f2bf(hi) << 16);
}
// v_cvt_pk_bf16_f32: dst.lo = bf16(lo), dst.hi = bf16(hi)  (RNE)
__device__ __forceinline__ u32 cvtpk(float lo, float hi) {
  u32 d;
  asm("v_cvt_pk_bf16_f32 %0, %1, %2" : "=v"(d) : "v"(lo), "v"(hi));
  return d;
}
// v_permlane32_swap_b32 a, b: a' = [a_lo, b_lo], b' = [a_hi, b_hi]
__device__ __forceinline__ void swap32(u32& a, u32& b) {
  asm volatile("v_permlane32_swap_b32 %0, %1" : "+v"(a), "+v"(b));
}
typedef union { uint4 u; short8 s; } U8;

__device__ __forceinline__ void barrier_full() {
  asm volatile("s_waitcnt vmcnt(0) lgkmcnt(0)" ::: "memory");
  __syncthreads();
}

// ---------------------------------------------------------------------------
// Prepass (unchanged): swizzled bf16 tile images in workspace.
//  K tiles:  [b][kt][row r=0..63][chunk c=0..15] at c ^ (r&15)
//  VT tiles: [b][kt][row d=0..127][chunk kc=0..7] at kc ^ (d&7)
// Block (z=0,kt=0,b=0) also builds the 512-entry complementary task table.
// ---------------------------------------------------------------------------
__global__ __launch_bounds__(256) void prep_kernel(const float* __restrict__ Kg,
                                                   const float* __restrict__ Vg,
                                                   const int* __restrict__ vlen,
                                                   uint4* __restrict__ Ksw,
                                                   uint4* __restrict__ Vsw,
                                                   int2* __restrict__ task) {
  __shared__ __align__(16) u32 Vu[64 * 65];
  __shared__ int sidx[32];
  const int kt = blockIdx.x, b = blockIdx.y, t = threadIdx.x;
  const bool tableblk = (blockIdx.z == 0) && (kt == 0) && (b == 0);

  if (tableblk && t < 64) {           // wave-parallel rank (reg-only)
    const int bb = t & 31;
    const int ntb = (vlen[bb] + 63) >> 6;
    int rank = 0;
#pragma unroll
    for (int j = 0; j < 32; j++) {
      const int ntj = __shfl(ntb, j);
      rank += (ntj > ntb) | ((ntj == ntb) & (j < bb));
    }
    if (t < 32) sidx[rank] = bb;
  }

  if (kt * 64 < vlen[b]) {
    if (blockIdx.z == 0) {
      const float* src = Kg + ((size_t)b * KSEQ + kt * 64) * DIM;
      uint4* dst = Ksw + ((size_t)b * NKT + kt) * 1024;
#pragma unroll
      for (int it = 0; it < 4; it++) {
        const int f = it * 256 + t, r = f >> 4, c = f & 15;
        floatx4 f0 = *(const floatx4*)(src + r * DIM + c * 8);
        floatx4 f1 = *(const floatx4*)(src + r * DIM + c * 8 + 4);
        uint4 o;
        o.x = pack2(f0[0], f0[1]); o.y = pack2(f0[2], f0[3]);
        o.z = pack2(f1[0], f1[1]); o.w = pack2(f1[2], f1[3]);
        dst[r * 16 + (c ^ (r & 15))] = o;
      }
    } else {
      const float* src = Vg + ((size_t)b * KSEQ + kt * 64) * DIM;
#pragma unroll
      for (int it = 0; it < 8; it++) {
        const int k = it * 8 + (t >> 5), c = t & 31;
        const floatx4 f = *(const floatx4*)(src + (size_t)k * DIM + c * 4);
        const int s = (k >> 3) & 4;
        Vu[k * 65 + ((2 * c) ^ s)]     = pack2(f[0], f[1]);
        Vu[k * 65 + ((2 * c + 1) ^ s)] = pack2(f[2], f[3]);
      }
      __syncthreads();
      uint4* dst = Vsw + ((size_t)b * NKT + kt) * 1024;
#pragma unroll
      for (int it = 0; it < 4; it++) {
        const int id = it * 256 + t;
        const int kc = id & 7, d = (id >> 3) & 127;
        const int col = (d >> 1) ^ (kc & 4);
        u32 r[8];
#pragma unroll
        for (int j = 0; j < 8; j++) r[j] = Vu[(kc * 8 + j) * 65 + col];
        const u32 sel = (d & 1) ? 0x07060302u : 0x05040100u;
        uint4 o;
        o.x = __builtin_amdgcn_perm(r[1], r[0], sel);
        o.y = __builtin_amdgcn_perm(r[3], r[2], sel);
        o.z = __builtin_amdgcn_perm(r[5], r[4], sel);
        o.w = __builtin_amdgcn_perm(r[7], r[6], sel);
        dst[d * 8 + (kc ^ (d & 7))] = o;
      }
    }
  }

  if (tableblk) {
    // Complementary table (QBLK=64, 512 tasks): XCD x gets ranks
    // {x,x+8,x+16,x+24}; breadth-first pairing (j, j+32) -> heavy+light/CU.
    __syncthreads();
    for (int l = t; l < 512; l += 256) {
      const int x = l & 7, j = l >> 3;
      int rank, q;
      if (j < 32) { rank = (j & 1) ? x + 8  : x;      q = j >> 1; }
      else        { rank = (j & 1) ? x + 16 : x + 24; q = (j - 32) >> 1; }
      task[l] = make_int2(sidx[rank], q << 6);
    }
  }
}

// ---------------------------------------------------------------------------
// Flash attention, 32x32x16 MFMA, swapped QK^T, register softmax, q+key-half
// wave split. Block = 4 waves x 256 thr, QBLK=64, grid 512 -> 2 blocks/CU =
// 8 waves/CU (2/SIMD; round-5's 1/SIMD was the latency bottleneck:
// MfmaUtil 6%, Occupancy 7%). Wave (qh=w&1, kh=w>>1) owns q-half qh and
// key-half kh of every tile: 8 QK^T MFMAs + 16 exp + 8 PV MFMAs per tile
// (half of round-5's chain). kh-halves accumulate privately; merged once in
// the epilogue via Kbuf-as-scratch. V is read per-lane straight from the
// L2-resident VT image (no Vbuf, no V DMA): loads issued right after the
// barrier, consumed ~400cy later after softmax. P never touches LDS
// (cvt_pk_bf16 + permlane32_swap, byte-identical to the verified r5 code).
// ---------------------------------------------------------------------------
typedef const __attribute__((address_space(1))) u32* as1p;
typedef __attribute__((address_space(3))) u32* as3p;
__device__ __forceinline__ void gl_lds16(const void* g, void* l) {
  __builtin_amdgcn_global_load_lds((as1p)g, (as3p)l, 16, 0, 0);
}

__global__ __launch_bounds__(256, 2) void attn_kernel(
    const float* __restrict__ Qg, const uint4* __restrict__ Ksw,
    const uint4* __restrict__ Vsw, const int* __restrict__ vlen,
    const int2* __restrict__ task, float* __restrict__ Og) {
  __shared__ __align__(16) short Kbuf[2][64 * 128];     // 32 KB dbuf; epilogue scratch
  __shared__ float Lred[2][32];

  const int2 tq = task[blockIdx.x];
  const int b = tq.x, q0 = tq.y;
  const int t = threadIdx.x, wave = t >> 6, lane = t & 63;
  const int qh = wave & 1, kh = wave >> 1;
  const int l31 = lane & 31, hi = lane >> 5, m15 = l31 & 15, m7 = l31 & 7;
  const int L  = vlen[b];
  const int nt = (L + 63) >> 6;

  const char*  Kt = (const char*)(Ksw + (size_t)b * NKT * 1024);
  const short* Vt = (const short*)(Vsw + (size_t)b * NKT * 1024);

  // ---- Q B-fragments for q-half qh: lane holds Q[q0+qh*32+l31][c*16+hi*8..] ----
  short8 qb[8];
  {
    const float* qrow = Qg + ((size_t)b * QLEN + q0 + qh * 32 + l31) * DIM;
#pragma unroll
    for (int c = 0; c < 8; c++) {
      floatx4 f0 = *(const floatx4*)(qrow + c * 16 + hi * 8);
      floatx4 f1 = *(const floatx4*)(qrow + c * 16 + hi * 8 + 4);
      short8 a;
      a[0] = (short)f2bf(f0[0]); a[1] = (short)f2bf(f0[1]);
      a[2] = (short)f2bf(f0[2]); a[3] = (short)f2bf(f0[3]);
      a[4] = (short)f2bf(f1[0]); a[5] = (short)f2bf(f1[1]);
      a[6] = (short)f2bf(f1[2]); a[7] = (short)f2bf(f1[3]);
      qb[c] = a;
    }
  }

  float lrow = 0.0f;
  floatx16 oacc[4];
#pragma unroll
  for (int dt = 0; dt < 4; dt++)
#pragma unroll
    for (int i = 0; i < 16; i++) oacc[dt][i] = 0.0f;

  // K DMA: 4 waves x 4 KB slices per 16 KB tile
#define ISSUE_K(tk, bb)                                                        \
  {                                                                            \
    const char* g_ = Kt + (size_t)(tk) * 16384 + wave * 4096 + lane * 16;      \
    _Pragma("unroll") for (int i_ = 0; i_ < 4; i_++)                           \
        gl_lds16(g_ + i_ * 1024, (char*)Kbuf[bb] + wave * 4096 + i_ * 1024);   \
  }

  ISSUE_K(0, 0);

  for (int tk = 0; tk < nt; tk++) {
    const int k0 = tk * 64;
    barrier_full();                        // DMA(tk) landed; buf[(tk+1)&1] free
    if (tk + 1 < nt) ISSUE_K(tk + 1, (tk + 1) & 1);
    const short* Kb_ = Kbuf[tk & 1];

    // ---- V B-fragments direct from the VT image (L2): issue early ----
    short8 vb[4][2];
    {
      const short* vt_ = Vt + (size_t)tk * 8192;
#pragma unroll
      for (int dt = 0; dt < 4; dt++) {
        const short* vr_ = vt_ + (dt * 32 + l31) * 64;
        vb[dt][0] = *(const short8*)(vr_ + ((kh * 4 + 0 + hi) ^ m7) * 8);
        vb[dt][1] = *(const short8*)(vr_ + ((kh * 4 + 2 + hi) ^ m7) * 8);
      }
    }

    // ---- swapped S = K Q^T for this wave's 32-key half: S[key][q] ----
    floatx16 s;
#pragma unroll
    for (int i = 0; i < 16; i++) s[i] = 0.0f;
    {
      const short* kr = Kb_ + (kh * 32 + l31) * 128;
      __builtin_amdgcn_s_setprio(1);
#pragma unroll
      for (int c = 0; c < 8; c++) {
        const short8 ka = *(const short8*)(kr + ((2 * c + hi) ^ m15) * 8);
        s = __builtin_amdgcn_mfma_f32_32x32x16_bf16(ka, qb[c], s, 0, 0, 0);
      }
      __builtin_amdgcn_s_setprio(0);
    }

    // ---- fixed-max softmax: p = exp(min(s*SCALE,30)), masked -> 0 ----
    if (k0 + kh * 32 + 32 <= L) {
#pragma unroll
      for (int r = 0; r < 16; r++) {
        s[r] = __expf(fminf(s[r] * SCALE, 30.0f));
        lrow += s[r];
      }
    } else {
#pragma unroll
      for (int r = 0; r < 16; r++) {
        const int ck = (r & 3) + 8 * (r >> 2) + 4 * hi;   // key within 32-tile
        const float a = (k0 + kh * 32 + ck < L)
                            ? __expf(fminf(s[r] * SCALE, 30.0f)) : 0.0f;
        s[r] = a;
        lrow += a;
      }
    }

    // ---- P fragments in-register (cvt_pk + permlane32_swap), then PV ----
    {
      u32 u0 = cvtpk(s[0], s[1]),   u1 = cvtpk(s[2], s[3]);
      u32 u2 = cvtpk(s[4], s[5]),   u3 = cvtpk(s[6], s[7]);
      swap32(u0, u2); swap32(u1, u3);
      u32 w0 = cvtpk(s[8], s[9]),   w1 = cvtpk(s[10], s[11]);
      u32 w2 = cvtpk(s[12], s[13]), w3 = cvtpk(s[14], s[15]);
      swap32(w0, w2); swap32(w1, w3);
      U8 pu0; pu0.u.x = u0; pu0.u.y = u1; pu0.u.z = u2; pu0.u.w = u3;
      U8 pu1; pu1.u.x = w0; pu1.u.y = w1; pu1.u.z = w2; pu1.u.w = w3;
      __builtin_amdgcn_s_setprio(1);
#pragma unroll
      for (int dt = 0; dt < 4; dt++) {
        oacc[dt] = __builtin_amdgcn_mfma_f32_32x32x16_bf16(pu0.s, vb[dt][0], oacc[dt], 0, 0, 0);
        oacc[dt] = __builtin_amdgcn_mfma_f32_32x32x16_bf16(pu1.s, vb[dt][1], oacc[dt], 0, 0, 0);
      }
      __builtin_amdgcn_s_setprio(0);
    }
  }

  // ---- epilogue: merge key-halves via Kbuf scratch, normalize, store ----
  lrow += __shfl_xor(lrow, 32);        // lane's 16 keys + partner's 16
  barrier_full();                      // all K reads done; Kbuf reusable
  float* scr = (float*)Kbuf;           // [dt*16+r][qh*64+lane], 8192 f32 = 32 KB
  if (kh == 1) {
    if (lane < 32) Lred[qh][l31] = lrow;
#pragma unroll
    for (int dt = 0; dt < 4; dt++)
#pragma unroll
      for (int r = 0; r < 16; r++)
        scr[(dt * 16 + r) * 128 + qh * 64 + lane] = oacc[dt][r];
  }
  __syncthreads();
  if (kh == 0) {
    const float ltot = lrow + Lred[qh][l31];
    const float inv_ = 1.0f / ltot;
    float iv[16];
#pragma unroll
    for (int r = 0; r < 16; r++)
      iv[r] = __shfl(inv_, (r & 3) + 8 * (r >> 2) + 4 * hi);
    float* obase = Og + ((size_t)b * QLEN + q0 + qh * 32) * DIM + l31;
#pragma unroll
    for (int dt = 0; dt < 4; dt++) {
#pragma unroll
      for (int r = 0; r < 16; r++) {
        const int rq = (r & 3) + 8 * (r >> 2) + 4 * hi;
        const float v = oacc[dt][r] + scr[(dt * 16 + r) * 128 + qh * 64 + lane];
        obase[(size_t)rq * DIM + dt * 32] = v * iv[r];
      }
    }
  }
#undef ISSUE_K
}

extern "C" void kernel_launch(void* const* d_in, const int* in_sizes, int n_in,
                              void* d_out, int out_size, void* d_ws, size_t ws_size,
                              hipStream_t stream) {
  const float* Qg = (const float*)d_in[0];
  const float* Kg = (const float*)d_in[1];
  const float* Vg = (const float*)d_in[2];
  const int*  vln = (const int*)d_in[3];
  uint4* Ksw = (uint4*)d_ws;                                      // 8 MiB
  uint4* Vsw = (uint4*)((char*)d_ws + (size_t)B_ * NKT * 16384);  // 8 MiB
  int2*  Tsk = (int2*)((char*)d_ws + 2 * (size_t)B_ * NKT * 16384);

  prep_kernel<<<dim3(NKT, B_, 2), 256, 0, stream>>>(Kg, Vg, vln, Ksw, Vsw, Tsk);
  attn_kernel<<<dim3(512), 256, 0, stream>>>(Qg, Ksw, Vsw, vln, Tsk,
                                             (float*)d_out);
}

// Round 7
// 116.653 us; speedup vs baseline: 1.0664x; 1.0014x over previous
//
#include <hip/hip_runtime.h>
#include <hip/hip_bf16.h>
#include <stdint.h>

#define B_    32
#define QLEN  1024
#define KSEQ  1024
#define DIM   128
#define NKT   (KSEQ / 64)              // 16 key-tiles of 64 per batch
#define SCALE 0.08838834764831845f     // 1/sqrt(128)

typedef __attribute__((ext_vector_type(8)))  short short8;
typedef __attribute__((ext_vector_type(4)))  float floatx4;
typedef __attribute__((ext_vector_type(16))) float floatx16;
typedef unsigned int u32;

__device__ __forceinline__ u32 f2bf(float x) {
  union { float f; u32 u; } v; v.f = x;
  return (v.u + 0x7FFF + ((v.u >> 16) & 1)) >> 16;   // RNE
}
__device__ __forceinline__ u32 pack2(float lo, float hi) {
  return f2bf(lo) | (f2bf(hi) << 16);
}
// v_cvt_pk_bf16_f32: dst.lo = bf16(lo), dst.hi = bf16(hi)  (RNE)
__device__ __forceinline__ u32 cvtpk(float lo, float hi) {
  u32 d;
  asm("v_cvt_pk_bf16_f32 %0, %1, %2" : "=v"(d) : "v"(lo), "v"(hi));
  return d;
}
// v_permlane32_swap_b32 a, b: a' = [a_lo, b_lo], b' = [a_hi, b_hi]
__device__ __forceinline__ void swap32(u32& a, u32& b) {
  asm volatile("v_permlane32_swap_b32 %0, %1" : "+v"(a), "+v"(b));
}
typedef union { uint4 u; short8 s; } U8;

// ---------------------------------------------------------------------------
// Prepass (unchanged): swizzled bf16 tile images in workspace.
//  K tiles:  [b][kt][row r=0..63][chunk c=0..15] at c ^ (r&15)
//  VT tiles: [b][kt][row d=0..127][chunk kc=0..7] at kc ^ (d&7)
// Block (z=0,kt=0,b=0) also builds the 512-entry complementary task table.
// ---------------------------------------------------------------------------
__global__ __launch_bounds__(256) void prep_kernel(const float* __restrict__ Kg,
                                                   const float* __restrict__ Vg,
                                                   const int* __restrict__ vlen,
                                                   uint4* __restrict__ Ksw,
                                                   uint4* __restrict__ Vsw,
                                                   int2* __restrict__ task) {
  __shared__ __align__(16) u32 Vu[64 * 65];
  __shared__ int sidx[32];
  const int kt = blockIdx.x, b = blockIdx.y, t = threadIdx.x;
  const bool tableblk = (blockIdx.z == 0) && (kt == 0) && (b == 0);

  if (tableblk && t < 64) {           // wave-parallel rank (reg-only)
    const int bb = t & 31;
    const int ntb = (vlen[bb] + 63) >> 6;
    int rank = 0;
#pragma unroll
    for (int j = 0; j < 32; j++) {
      const int ntj = __shfl(ntb, j);
      rank += (ntj > ntb) | ((ntj == ntb) & (j < bb));
    }
    if (t < 32) sidx[rank] = bb;
  }

  if (kt * 64 < vlen[b]) {
    if (blockIdx.z == 0) {
      const float* src = Kg + ((size_t)b * KSEQ + kt * 64) * DIM;
      uint4* dst = Ksw + ((size_t)b * NKT + kt) * 1024;
#pragma unroll
      for (int it = 0; it < 4; it++) {
        const int f = it * 256 + t, r = f >> 4, c = f & 15;
        floatx4 f0 = *(const floatx4*)(src + r * DIM + c * 8);
        floatx4 f1 = *(const floatx4*)(src + r * DIM + c * 8 + 4);
        uint4 o;
        o.x = pack2(f0[0], f0[1]); o.y = pack2(f0[2], f0[3]);
        o.z = pack2(f1[0], f1[1]); o.w = pack2(f1[2], f1[3]);
        dst[r * 16 + (c ^ (r & 15))] = o;
      }
    } else {
      const float* src = Vg + ((size_t)b * KSEQ + kt * 64) * DIM;
#pragma unroll
      for (int it = 0; it < 8; it++) {
        const int k = it * 8 + (t >> 5), c = t & 31;
        const floatx4 f = *(const floatx4*)(src + (size_t)k * DIM + c * 4);
        const int s = (k >> 3) & 4;
        Vu[k * 65 + ((2 * c) ^ s)]     = pack2(f[0], f[1]);
        Vu[k * 65 + ((2 * c + 1) ^ s)] = pack2(f[2], f[3]);
      }
      __syncthreads();
      uint4* dst = Vsw + ((size_t)b * NKT + kt) * 1024;
#pragma unroll
      for (int it = 0; it < 4; it++) {
        const int id = it * 256 + t;
        const int kc = id & 7, d = (id >> 3) & 127;
        const int col = (d >> 1) ^ (kc & 4);
        u32 r[8];
#pragma unroll
        for (int j = 0; j < 8; j++) r[j] = Vu[(kc * 8 + j) * 65 + col];
        const u32 sel = (d & 1) ? 0x07060302u : 0x05040100u;
        uint4 o;
        o.x = __builtin_amdgcn_perm(r[1], r[0], sel);
        o.y = __builtin_amdgcn_perm(r[3], r[2], sel);
        o.z = __builtin_amdgcn_perm(r[5], r[4], sel);
        o.w = __builtin_amdgcn_perm(r[7], r[6], sel);
        dst[d * 8 + (kc ^ (d & 7))] = o;
      }
    }
  }

  if (tableblk) {
    // Complementary table (QBLK=64, 512 tasks): XCD x gets ranks
    // {x,x+8,x+16,x+24}; breadth-first pairing (j, j+32) -> heavy+light/CU.
    __syncthreads();
    for (int l = t; l < 512; l += 256) {
      const int x = l & 7, j = l >> 3;
      int rank, q;
      if (j < 32) { rank = (j & 1) ? x + 8  : x;      q = j >> 1; }
      else        { rank = (j & 1) ? x + 16 : x + 24; q = (j - 32) >> 1; }
      task[l] = make_int2(sidx[rank], q << 6);
    }
  }
}

// ---------------------------------------------------------------------------
// Flash attention, 32x32x16 MFMA, swapped QK^T, register softmax, q+key-half
// wave split — now with a BARRIER-FREE main loop. Round 6 still drained
// vmcnt(0)+syncthreads once per k-tile to service the K global_load_lds
// staging, coupling all 4 waves to the slowest DMA slice. Round 6 also
// proved per-lane direct-from-L2 reads of the swizzled image work (V path).
// So: K fragments are now read per-lane from the L2-resident K image too,
// double-buffered in REGISTERS (hand-unrolled x2, static names). No LDS
// staging, no barriers until the single epilogue kh-merge; each wave runs
// fully asynchronously. Per tile per wave: 8 K-frag loads (prefetched one
// tile ahead) + 8 V-frag loads (issued at iter top, consumed after softmax,
// ~400cy later) + 8 QK^T MFMA + 16 exp + 8 PV MFMA. P never touches LDS
// (cvt_pk_bf16 + permlane32_swap, byte-identical to the verified r5/r6 code).
// Block = 4 waves (qh=w&1, kh=w>>1), QBLK=64, grid 512 = 2 blocks/CU.
// ---------------------------------------------------------------------------
__global__ __launch_bounds__(256, 2) void attn_kernel(
    const float* __restrict__ Qg, const uint4* __restrict__ Ksw,
    const uint4* __restrict__ Vsw, const int* __restrict__ vlen,
    const int2* __restrict__ task, float* __restrict__ Og) {
  __shared__ float scr[64 * 128];      // 32 KB epilogue merge scratch
  __shared__ float Lred[2][32];

  const int2 tq = task[blockIdx.x];
  const int b = tq.x, q0 = tq.y;
  const int t = threadIdx.x, wave = t >> 6, lane = t & 63;
  const int qh = wave & 1, kh = wave >> 1;
  const int l31 = lane & 31, hi = lane >> 5, m15 = l31 & 15, m7 = l31 & 7;
  const int L  = vlen[b];
  const int nt = (L + 63) >> 6;
  const int krow = kh * 32 + l31;

  const short* KtS = (const short*)(Ksw + (size_t)b * NKT * 1024);
  const short* Vt  = (const short*)(Vsw + (size_t)b * NKT * 1024);

  // ---- Q B-fragments for q-half qh: lane holds Q[q0+qh*32+l31][c*16+hi*8..] ----
  short8 qb[8];
  {
    const float* qrow = Qg + ((size_t)b * QLEN + q0 + qh * 32 + l31) * DIM;
#pragma unroll
    for (int c = 0; c < 8; c++) {
      floatx4 f0 = *(const floatx4*)(qrow + c * 16 + hi * 8);
      floatx4 f1 = *(const floatx4*)(qrow + c * 16 + hi * 8 + 4);
      short8 a;
      a[0] = (short)f2bf(f0[0]); a[1] = (short)f2bf(f0[1]);
      a[2] = (short)f2bf(f0[2]); a[3] = (short)f2bf(f0[3]);
      a[4] = (short)f2bf(f1[0]); a[5] = (short)f2bf(f1[1]);
      a[6] = (short)f2bf(f1[2]); a[7] = (short)f2bf(f1[3]);
      qb[c] = a;
    }
  }

  float lrow = 0.0f;
  floatx16 oacc[4];
#pragma unroll
  for (int dt = 0; dt < 4; dt++)
#pragma unroll
    for (int i = 0; i < 16; i++) oacc[dt][i] = 0.0f;

  // K fragment loads for one tile into a named register buffer (8 x 16B).
  // Per-lane addr: row krow, chunks (2c+hi)^m15 of the swizzled K image.
#define LOAD_K(DST, tkv)                                                       \
  {                                                                            \
    const short* kp_ = KtS + (size_t)(tkv) * 8192 + krow * 128;                \
    _Pragma("unroll") for (int c_ = 0; c_ < 8; c_++)                           \
      DST[c_] = *(const short8*)(kp_ + ((2 * c_ + hi) ^ m15) * 8);             \
  }

  // One k-tile body: V issue -> QK^T(KF) -> fixed-max softmax -> PV.
#define BODY(KF, tkv)                                                          \
  {                                                                            \
    const int k0_ = (tkv) * 64;                                                \
    short8 vb[4][2];                                                           \
    {                                                                          \
      const short* vt_ = Vt + (size_t)(tkv) * 8192;                            \
      _Pragma("unroll") for (int dt = 0; dt < 4; dt++) {                       \
        const short* vr_ = vt_ + (dt * 32 + l31) * 64;                         \
        vb[dt][0] = *(const short8*)(vr_ + ((kh * 4 + 0 + hi) ^ m7) * 8);      \
        vb[dt][1] = *(const short8*)(vr_ + ((kh * 4 + 2 + hi) ^ m7) * 8);      \
      }                                                                        \
    }                                                                          \
    floatx16 s;                                                                \
    _Pragma("unroll") for (int i = 0; i < 16; i++) s[i] = 0.0f;                \
    __builtin_amdgcn_s_setprio(1);                                             \
    _Pragma("unroll") for (int c = 0; c < 8; c++)                              \
      s = __builtin_amdgcn_mfma_f32_32x32x16_bf16(KF[c], qb[c], s, 0, 0, 0);   \
    __builtin_amdgcn_s_setprio(0);                                             \
    if (k0_ + kh * 32 + 32 <= L) {                                             \
      _Pragma("unroll") for (int r = 0; r < 16; r++) {                         \
        s[r] = __expf(fminf(s[r] * SCALE, 30.0f));                             \
        lrow += s[r];                                                          \
      }                                                                        \
    } else {                                                                   \
      _Pragma("unroll") for (int r = 0; r < 16; r++) {                         \
        const int ck = (r & 3) + 8 * (r >> 2) + 4 * hi;                        \
        const float a = (k0_ + kh * 32 + ck < L)                               \
                            ? __expf(fminf(s[r] * SCALE, 30.0f)) : 0.0f;       \
        s[r] = a;                                                              \
        lrow += a;                                                             \
      }                                                                        \
    }                                                                          \
    {                                                                          \
      u32 u0 = cvtpk(s[0], s[1]),   u1 = cvtpk(s[2], s[3]);                    \
      u32 u2 = cvtpk(s[4], s[5]),   u3 = cvtpk(s[6], s[7]);                    \
      swap32(u0, u2); swap32(u1, u3);                                          \
      u32 w0 = cvtpk(s[8], s[9]),   w1 = cvtpk(s[10], s[11]);                  \
      u32 w2 = cvtpk(s[12], s[13]), w3 = cvtpk(s[14], s[15]);                  \
      swap32(w0, w2); swap32(w1, w3);                                          \
      U8 pu0; pu0.u.x = u0; pu0.u.y = u1; pu0.u.z = u2; pu0.u.w = u3;          \
      U8 pu1; pu1.u.x = w0; pu1.u.y = w1; pu1.u.z = w2; pu1.u.w = w3;          \
      __builtin_amdgcn_s_setprio(1);                                           \
      _Pragma("unroll") for (int dt = 0; dt < 4; dt++) {                       \
        oacc[dt] = __builtin_amdgcn_mfma_f32_32x32x16_bf16(pu0.s, vb[dt][0],   \
                                                           oacc[dt], 0, 0, 0);\
        oacc[dt] = __builtin_amdgcn_mfma_f32_32x32x16_bf16(pu1.s, vb[dt][1],   \
                                                           oacc[dt], 0, 0, 0);\
      }                                                                        \
      __builtin_amdgcn_s_setprio(0);                                           \
    }                                                                          \
  }

  // ---- barrier-free main loop: register-double-buffered K, x2 unroll ----
  short8 ka[8], kb[8];
  LOAD_K(ka, 0);
  int tk = 0;
  for (;;) {
    if (tk + 1 < nt) LOAD_K(kb, tk + 1);     // prefetch overlaps BODY(ka)
    BODY(ka, tk);
    if (++tk == nt) break;
    if (tk + 1 < nt) LOAD_K(ka, tk + 1);     // prefetch overlaps BODY(kb)
    BODY(kb, tk);
    if (++tk == nt) break;
  }

  // ---- epilogue: merge key-halves via LDS scratch, normalize, store ----
  lrow += __shfl_xor(lrow, 32);        // lane's 16 keys + partner's 16
  if (kh == 1) {
    if (lane < 32) Lred[qh][l31] = lrow;
#pragma unroll
    for (int dt = 0; dt < 4; dt++)
#pragma unroll
      for (int r = 0; r < 16; r++)
        scr[(dt * 16 + r) * 128 + qh * 64 + lane] = oacc[dt][r];
  }
  __syncthreads();
  if (kh == 0) {
    const float ltot = lrow + Lred[qh][l31];
    const float inv_ = 1.0f / ltot;
    float iv[16];
#pragma unroll
    for (int r = 0; r < 16; r++)
      iv[r] = __shfl(inv_, (r & 3) + 8 * (r >> 2) + 4 * hi);
    float* obase = Og + ((size_t)b * QLEN + q0 + qh * 32) * DIM + l31;
#pragma unroll
    for (int dt = 0; dt < 4; dt++) {
#pragma unroll
      for (int r = 0; r < 16; r++) {
        const int rq = (r & 3) + 8 * (r >> 2) + 4 * hi;
        const float v = oacc[dt][r] + scr[(dt * 16 + r) * 128 + qh * 64 + lane];
        obase[(size_t)rq * DIM + dt * 32] = v * iv[r];
      }
    }
  }
#undef LOAD_K
#undef BODY
}

extern "C" void kernel_launch(void* const* d_in, const int* in_sizes, int n_in,
                              void* d_out, int out_size, void* d_ws, size_t ws_size,
                              hipStream_t stream) {
  const float* Qg = (const float*)d_in[0];
  const float* Kg = (const float*)d_in[1];
  const float* Vg = (const float*)d_in[2];
  const int*  vln = (const int*)d_in[3];
  uint4* Ksw = (uint4*)d_ws;                                      // 8 MiB
  uint4* Vsw = (uint4*)((char*)d_ws + (size_t)B_ * NKT * 16384);  // 8 MiB
  int2*  Tsk = (int2*)((char*)d_ws + 2 * (size_t)B_ * NKT * 16384);

  prep_kernel<<<dim3(NKT, B_, 2), 256, 0, stream>>>(Kg, Vg, vln, Ksw, Vsw, Tsk);
  attn_kernel<<<dim3(512), 256, 0, stream>>>(Qg, Ksw, Vsw, vln, Tsk,
                                             (float*)d_out);
}